// Round 2
// 228.841 us; speedup vs baseline: 1.0172x; 1.0172x over previous
//
#include <hip/hip_runtime.h>

typedef unsigned short u16;
typedef __bf16 bf16x8 __attribute__((ext_vector_type(8)));
typedef float f32x4 __attribute__((ext_vector_type(4)));

union B8 { uint4 u; bf16x8 v; };
union U8 { u16 s[8]; uint4 u; };

#define NQ 2048
#define NK 2048
#define ND 128

template<int C>
__device__ __forceinline__ float dppf(float x) {
  int v = __builtin_bit_cast(int, x);
  int r = __builtin_amdgcn_update_dpp(v, v, C, 0xF, 0xF, true);
  return __builtin_bit_cast(float, r);
}
__device__ __forceinline__ float rowmax16(float x) {
  x = fmaxf(x, dppf<0xB1>(x));   // quad_perm xor1
  x = fmaxf(x, dppf<0x4E>(x));   // quad_perm xor2
  x = fmaxf(x, dppf<0x141>(x));  // row_half_mirror
  x = fmaxf(x, dppf<0x140>(x));  // row_mirror
  return x;
}
__device__ __forceinline__ float rowsum16(float x) {
  x += dppf<0xB1>(x);
  x += dppf<0x4E>(x);
  x += dppf<0x141>(x);
  x += dppf<0x140>(x);
  return x;
}

__device__ __forceinline__ bf16x8 cvt8(float4 a, float4 b) {
  bf16x8 r;
  r[0] = (__bf16)a.x; r[1] = (__bf16)a.y; r[2] = (__bf16)a.z; r[3] = (__bf16)a.w;
  r[4] = (__bf16)b.x; r[5] = (__bf16)b.y; r[6] = (__bf16)b.z; r[7] = (__bf16)b.w;
  return r;
}

// Flash attention fwd, fp32 I/O, bf16 MFMA compute.
// 256 threads = 4 waves; wave owns 32 Q rows (2 m-blocks sharing every K/V B-frag).
// Q-tile 128, K-tile 64 -> grid 256 = 1 block/CU; K/V staged once per 128 Q rows.
// Datapath (K XOR-swizzle, V d-major scatter, per-wave P granule-XOR) identical to
// the verified 16-row kernel; only the mb dimension is new.
__global__ __launch_bounds__(256, 1)
void flash_fwd(const float* __restrict__ qg, const float* __restrict__ kg,
               const float* __restrict__ vg, const int* __restrict__ vlg,
               float* __restrict__ og)
{
  // K tile (bf16): 64 rows x 128 d, granule(8)-XOR: (row,g) at row*128+((g^(row&15))<<3)
  __shared__ __align__(16) u16 sK[64 * 128];
  // V tile (bf16) d-major: 128 d x 64 kv: (d,kv) at d*64+(((kv>>3)^(d&7))<<3)+(kv&7)
  __shared__ __align__(16) u16 sV[128 * 64];
  // P per wave: 32 rows x 64, granule-XOR: (row,c) at row*64+((((c>>3)^(row&7))<<3))+(c&7)
  __shared__ __align__(16) u16 sP[4][32 * 64];

  const int tid  = threadIdx.x;
  const int lane = tid & 63;
  const int wv   = tid >> 6;     // wave 0..3
  const int n    = lane & 15;
  const int quad = lane >> 4;

  const int bi = blockIdx.x;
  // XCD-swizzle: XCD x (= bi&7) serves batches {2x, 2x+1}; 4 MB K+V per XCD fits L2
  const int b  = ((bi & 7) << 1) | ((bi >> 3) & 1);
  const int qt = bi >> 4;

  const int vl = vlg[b];
  const int nt = (vl + 63) >> 6;

  const int qrow0 = qt * 128 + wv * 32;

  // Q fragments (A-layout: A[m=lane&15][k=quad*8+j]), live whole loop
  bf16x8 qf[2][4];
  #pragma unroll
  for (int mb = 0; mb < 2; ++mb)
    #pragma unroll
    for (int c = 0; c < 4; ++c) {
      const float* qp = qg + (size_t)(b * NQ + qrow0 + mb * 16 + n) * ND + c * 32 + quad * 8;
      qf[mb][c] = cvt8(*(const float4*)qp, *(const float4*)(qp + 4));
    }

  f32x4 O[2][8];
  float mst[2][4], lst[2][4];
  #pragma unroll
  for (int mb = 0; mb < 2; ++mb) {
    #pragma unroll
    for (int f = 0; f < 8; ++f) O[mb][f] = (f32x4){0.f, 0.f, 0.f, 0.f};
    #pragma unroll
    for (int r = 0; r < 4; ++r) { mst[mb][r] = -__builtin_inff(); lst[mb][r] = 0.f; }
  }

  const float* kb = kg + (size_t)(b * NK) * ND;
  const float* vb = vg + (size_t)(b * NK) * ND;

  // Staging: thread owns row srow (0..63), col-quarter scq (32 cols)
  const int srow = tid >> 2, scq = tid & 3;
  bf16x8 kreg[4], vreg[4];

  auto kload = [&](int t) {
    const float* src = kb + (size_t)(t * 64 + srow) * ND + scq * 32;
    #pragma unroll
    for (int c = 0; c < 4; ++c)
      kreg[c] = cvt8(*(const float4*)(src + c * 8), *(const float4*)(src + c * 8 + 4));
  };
  auto kstore = [&]() {
    #pragma unroll
    for (int c = 0; c < 4; ++c) {
      B8 tt; tt.v = kreg[c];
      *(uint4*)(&sK[srow * 128 + (((scq * 4 + c) ^ (srow & 15)) << 3)]) = tt.u;
    }
  };
  auto vload = [&](int t) {
    const float* src = vb + (size_t)(t * 64 + srow) * ND + scq * 32;
    #pragma unroll
    for (int c = 0; c < 4; ++c)
      vreg[c] = cvt8(*(const float4*)(src + c * 8), *(const float4*)(src + c * 8 + 4));
  };
  auto vstore = [&]() {    // transpose-scatter: kv = srow, d = scq*32+c*8+j (d&7 == j)
    #pragma unroll
    for (int c = 0; c < 4; ++c) {
      B8 x; x.v = vreg[c];
      U8 tt; tt.u = x.u;
      #pragma unroll
      for (int j = 0; j < 8; ++j) {
        int d = scq * 32 + c * 8 + j;
        sV[d * 64 + (((srow >> 3) ^ j) << 3) + (srow & 7)] = tt.s[j];
      }
    }
  };

  kload(0); vload(0);
  kstore(); vstore();

  constexpr float CEXP = 0.08838834764831845f * 1.44269504088896340f; // log2e/sqrt(128)

  u16* Pw = sP[wv];

  for (int t = 0; t < nt; ++t) {
    __syncthreads();                   // barrier1: tile t K/V visible in LDS
    if (t + 1 < nt) { kload(t + 1); vload(t + 1); }  // global->regs, overlaps compute

    // ---- S = Q * K^T  (32 MFMAs, 16 b128 reads: B-frag reused across 2 m-blocks) ----
    f32x4 S[2][4];
    #pragma unroll
    for (int mb = 0; mb < 2; ++mb)
      #pragma unroll
      for (int jn = 0; jn < 4; ++jn) S[mb][jn] = (f32x4){0.f, 0.f, 0.f, 0.f};
    #pragma unroll
    for (int c = 0; c < 4; ++c)
      #pragma unroll
      for (int jn = 0; jn < 4; ++jn) {
        B8 bb;   // B-frag: K[col=jn*16+n][d=c*32+quad*8+j], unswizzle (row&15 == n)
        bb.u = *(const uint4*)(&sK[(jn * 16 + n) * 128 + (((c * 4 + quad) ^ n) << 3)]);
        S[0][jn] = __builtin_amdgcn_mfma_f32_16x16x32_bf16(qf[0][c], bb.v, S[0][jn], 0, 0, 0);
        S[1][jn] = __builtin_amdgcn_mfma_f32_16x16x32_bf16(qf[1][c], bb.v, S[1][jn], 0, 0, 0);
      }

    // ---- mask tail columns (kv >= vl) ----
    if (t * 64 + 64 > vl) {
      #pragma unroll
      for (int jn = 0; jn < 4; ++jn) {
        const bool msk = (t * 64 + jn * 16 + n) >= vl;
        #pragma unroll
        for (int r = 0; r < 4; ++r) {
          S[0][jn][r] = msk ? -1e30f : S[0][jn][r];
          S[1][jn][r] = msk ? -1e30f : S[1][jn][r];
        }
      }
    }

    // ---- online softmax (8 independent row-chains) ----
    float al[2][4];
    #pragma unroll
    for (int mb = 0; mb < 2; ++mb)
      #pragma unroll
      for (int r = 0; r < 4; ++r) {
        float mx = fmaxf(fmaxf(S[mb][0][r], S[mb][1][r]), fmaxf(S[mb][2][r], S[mb][3][r]));
        mx = rowmax16(mx);
        float mnew = fmaxf(mst[mb][r], mx);
        float a = __builtin_exp2f((mst[mb][r] - mnew) * CEXP);
        mst[mb][r] = mnew;
        float ssum = 0.f;
        #pragma unroll
        for (int jn = 0; jn < 4; ++jn) {
          float p = __builtin_exp2f((S[mb][jn][r] - mnew) * CEXP);
          S[mb][jn][r] = p;
          ssum += p;
        }
        ssum = rowsum16(ssum);
        lst[mb][r] = lst[mb][r] * a + ssum;
        al[mb][r] = a;
      }
    #pragma unroll
    for (int mb = 0; mb < 2; ++mb)
      #pragma unroll
      for (int f = 0; f < 8; ++f) {
        O[mb][f][0] *= al[mb][0]; O[mb][f][1] *= al[mb][1];
        O[mb][f][2] *= al[mb][2]; O[mb][f][3] *= al[mb][3];
      }

    // P (C-layout) -> per-wave LDS (granule-XOR); same-wave DS order guarantees RAW
    #pragma unroll
    for (int mb = 0; mb < 2; ++mb)
      #pragma unroll
      for (int jn = 0; jn < 4; ++jn)
        #pragma unroll
        for (int r = 0; r < 4; ++r) {
          int row = mb * 16 + quad * 4 + r;
          __bf16 h = (__bf16)S[mb][jn][r];
          Pw[row * 64 + (((jn * 2 + (n >> 3)) ^ (row & 7)) << 3) + (n & 7)]
              = __builtin_bit_cast(u16, h);
        }

    // ---- O += P * V  (32 MFMAs; V B-frag read once, reused across 2 m-blocks) ----
    #pragma unroll
    for (int kc = 0; kc < 2; ++kc) {
      bf16x8 af[2];
      #pragma unroll
      for (int mb = 0; mb < 2; ++mb) {
        B8 ta;   // A-frag: P[m=mb*16+n][k=kc*32+quad*8+j]
        ta.u = *(const uint4*)(&Pw[(mb * 16 + n) * 64 + (((kc * 4 + quad) ^ (n & 7)) << 3)]);
        af[mb] = ta.v;
      }
      #pragma unroll
      for (int f = 0; f < 8; ++f) {
        int d = f * 16 + n;                 // d&7 == n&7
        B8 bb;   // B-frag: V[k=kv][n=d] from d-major sV, unswizzle
        bb.u = *(const uint4*)(&sV[d * 64 + (((kc * 4 + quad) ^ (n & 7)) << 3)]);
        O[0][f] = __builtin_amdgcn_mfma_f32_16x16x32_bf16(af[0], bb.v, O[0][f], 0, 0, 0);
        O[1][f] = __builtin_amdgcn_mfma_f32_16x16x32_bf16(af[1], bb.v, O[1][f], 0, 0, 0);
      }
    }

    __syncthreads();                   // barrier2: all waves done reading tile t
    if (t + 1 < nt) { kstore(); vstore(); }   // regs -> LDS for tile t+1
  }

  // ---- epilogue: O / l, store fp32 ----
  #pragma unroll
  for (int mb = 0; mb < 2; ++mb)
    #pragma unroll
    for (int r = 0; r < 4; ++r) {
      const float rl = 1.0f / lst[mb][r];
      const int qrow = qrow0 + mb * 16 + quad * 4 + r;
      float* op = og + (size_t)(b * NQ + qrow) * ND + n;
      #pragma unroll
      for (int f = 0; f < 8; ++f)
        op[f * 16] = O[mb][f][r] * rl;
    }
}

extern "C" void kernel_launch(void* const* d_in, const int* in_sizes, int n_in,
                              void* d_out, int out_size, void* d_ws, size_t ws_size,
                              hipStream_t stream) {
  const float* q  = (const float*)d_in[0];
  const float* k  = (const float*)d_in[1];
  const float* v  = (const float*)d_in[2];
  const int*  vl  = (const int*)d_in[3];
  float* out = (float*)d_out;
  (void)d_ws; (void)ws_size;

  hipLaunchKernelGGL(flash_fwd, dim3(256), dim3(256), 0, stream, q, k, v, vl, out);
}

// Round 3
// 225.229 us; speedup vs baseline: 1.0335x; 1.0160x over previous
//
#include <hip/hip_runtime.h>

typedef unsigned short u16;
typedef __bf16 bf16x8 __attribute__((ext_vector_type(8)));
typedef float f32x4 __attribute__((ext_vector_type(4)));

union B8 { uint4 u; bf16x8 v; };
union U8 { u16 s[8]; uint4 u; };

#define NQ 2048
#define NK 2048
#define ND 128

template<int C>
__device__ __forceinline__ float dppf(float x) {
  int v = __builtin_bit_cast(int, x);
  int r = __builtin_amdgcn_update_dpp(v, v, C, 0xF, 0xF, true);
  return __builtin_bit_cast(float, r);
}
__device__ __forceinline__ float rowmax16(float x) {
  x = fmaxf(x, dppf<0xB1>(x));   // quad_perm xor1
  x = fmaxf(x, dppf<0x4E>(x));   // quad_perm xor2
  x = fmaxf(x, dppf<0x141>(x));  // row_half_mirror
  x = fmaxf(x, dppf<0x140>(x));  // row_mirror
  return x;
}
__device__ __forceinline__ float rowsum16(float x) {
  x += dppf<0xB1>(x);
  x += dppf<0x4E>(x);
  x += dppf<0x141>(x);
  x += dppf<0x140>(x);
  return x;
}

__device__ __forceinline__ bf16x8 cvt8(float4 a, float4 b) {
  bf16x8 r;
  r[0] = (__bf16)a.x; r[1] = (__bf16)a.y; r[2] = (__bf16)a.z; r[3] = (__bf16)a.w;
  r[4] = (__bf16)b.x; r[5] = (__bf16)b.y; r[6] = (__bf16)b.z; r[7] = (__bf16)b.w;
  return r;
}

// Flash attention fwd, fp32 I/O, bf16 MFMA compute.
// 1024 threads = 16 waves = 8 q-waves (16 rows each, Q-tile 128) x 2 kv-groups.
// Group g processes KV tiles t = 2i+g into private (m,l,O); single end-of-kernel
// merge in LDS. 4 waves/SIMD for latency hiding; critical serial depth halves.
// Per-wave datapath (K XOR-swizzle, V d-major scatter, P granule-XOR) is the
// verified 16-row path, unchanged.
__global__ __launch_bounds__(1024, 4)
void flash_fwd(const float* __restrict__ qg, const float* __restrict__ kg,
               const float* __restrict__ vg, const int* __restrict__ vlg,
               float* __restrict__ og)
{
  // K tiles (bf16), one per group: 64 rows x 128 d, (row,g8) at row*128+((g8^(row&15))<<3)
  __shared__ __align__(16) u16 sK[2][64 * 128];
  // V tiles (bf16) d-major: 128 d x 64 kv: (d,kv) at d*64+(((kv>>3)^(d&7))<<3)+(kv&7)
  __shared__ __align__(16) u16 sV[2][64 * 128];
  // P per wave: 16 rows x 64, granule-XOR: (row,c) at row*64+((((c>>3)^(row&7))<<3))+(c&7)
  __shared__ __align__(16) u16 sP[16][16 * 64];

  const int tid  = threadIdx.x;
  const int lane = tid & 63;
  const int wv   = tid >> 6;     // wave 0..15
  const int qw   = wv & 7;       // q-wave 0..7
  const int grp  = wv >> 3;      // kv-group 0/1
  const int n    = lane & 15;
  const int quad = lane >> 4;

  const int bi = blockIdx.x;
  // XCD-swizzle: XCD x (= bi&7) serves batches {2x, 2x+1}; 4 MB K+V per XCD fits L2
  const int b  = ((bi & 7) << 1) | ((bi >> 3) & 1);
  const int qt = bi >> 4;

  const int vl = vlg[b];
  const int nt = (vl + 63) >> 6;

  const int qrow0 = qt * 128 + qw * 16;

  // Q fragments (A-layout: A[m=lane&15][k=quad*8+j]), live whole loop
  bf16x8 qf[4];
  #pragma unroll
  for (int c = 0; c < 4; ++c) {
    const float* qp = qg + (size_t)(b * NQ + qrow0 + n) * ND + c * 32 + quad * 8;
    qf[c] = cvt8(*(const float4*)qp, *(const float4*)(qp + 4));
  }

  f32x4 O[8];
  float mst[4], lst[4];
  #pragma unroll
  for (int f = 0; f < 8; ++f) O[f] = (f32x4){0.f, 0.f, 0.f, 0.f};
  #pragma unroll
  for (int r = 0; r < 4; ++r) { mst[r] = -__builtin_inff(); lst[r] = 0.f; }

  const float* kb = kg + (size_t)(b * NK) * ND;
  const float* vb = vg + (size_t)(b * NK) * ND;

  // Staging: group's 512 threads stage its own tile; thread owns row srow, 16-col chunk sc8
  const int stid = tid & 511;
  const int srow = stid >> 3, sc8 = stid & 7;
  bf16x8 kreg[2], vreg[2];

  auto kload = [&](int t) {
    const float* src = kb + (size_t)(t * 64 + srow) * ND + sc8 * 16;
    #pragma unroll
    for (int c = 0; c < 2; ++c)
      kreg[c] = cvt8(*(const float4*)(src + c * 8), *(const float4*)(src + c * 8 + 4));
  };
  auto kstore = [&]() {
    #pragma unroll
    for (int c = 0; c < 2; ++c) {
      B8 tt; tt.v = kreg[c];
      *(uint4*)(&sK[grp][srow * 128 + (((sc8 * 2 + c) ^ (srow & 15)) << 3)]) = tt.u;
    }
  };
  auto vload = [&](int t) {
    const float* src = vb + (size_t)(t * 64 + srow) * ND + sc8 * 16;
    #pragma unroll
    for (int c = 0; c < 2; ++c)
      vreg[c] = cvt8(*(const float4*)(src + c * 8), *(const float4*)(src + c * 8 + 4));
  };
  auto vstore = [&]() {    // transpose-scatter: kv = srow, d = sc8*16+c*8+j (d&7 == j)
    #pragma unroll
    for (int c = 0; c < 2; ++c) {
      B8 x; x.v = vreg[c];
      U8 tt; tt.u = x.u;
      #pragma unroll
      for (int j = 0; j < 8; ++j) {
        int d = sc8 * 16 + c * 8 + j;
        sV[grp][d * 64 + (((srow >> 3) ^ j) << 3) + (srow & 7)] = tt.s[j];
      }
    }
  };

  if (grp < nt) { kload(grp); vload(grp); kstore(); vstore(); }

  constexpr float CEXP = 0.08838834764831845f * 1.44269504088896340f; // log2e/sqrt(128)

  u16* Pw = sP[wv];
  const u16* Kg = sK[grp];
  const u16* Vg = sV[grp];

  const int NS = (nt + 1) >> 1;
  for (int i = 0; i < NS; ++i) {
    __syncthreads();                   // barrier1: super-iter i tiles visible in LDS
    const int t  = 2 * i + grp;
    const int tn = t + 2;
    if (tn < nt) { kload(tn); vload(tn); }  // global->regs, overlaps compute

    if (t < nt) {
      // ---- S = Q * K^T  (16 MFMAs, 16 b128 reads) ----
      f32x4 S[4];
      #pragma unroll
      for (int jn = 0; jn < 4; ++jn) S[jn] = (f32x4){0.f, 0.f, 0.f, 0.f};
      #pragma unroll
      for (int c = 0; c < 4; ++c)
        #pragma unroll
        for (int jn = 0; jn < 4; ++jn) {
          B8 bb;   // B-frag: K[col=jn*16+n][d=c*32+quad*8+j], unswizzle (row&15 == n)
          bb.u = *(const uint4*)(&Kg[(jn * 16 + n) * 128 + (((c * 4 + quad) ^ n) << 3)]);
          S[jn] = __builtin_amdgcn_mfma_f32_16x16x32_bf16(qf[c], bb.v, S[jn], 0, 0, 0);
        }

      // ---- mask tail columns (kv >= vl) ----
      if (t * 64 + 64 > vl) {
        #pragma unroll
        for (int jn = 0; jn < 4; ++jn) {
          const bool msk = (t * 64 + jn * 16 + n) >= vl;
          #pragma unroll
          for (int r = 0; r < 4; ++r)
            S[jn][r] = msk ? -1e30f : S[jn][r];
        }
      }

      // ---- online softmax (4 independent row-chains) ----
      float al[4];
      #pragma unroll
      for (int r = 0; r < 4; ++r) {
        float mx = fmaxf(fmaxf(S[0][r], S[1][r]), fmaxf(S[2][r], S[3][r]));
        mx = rowmax16(mx);
        float mnew = fmaxf(mst[r], mx);
        float a = __builtin_exp2f((mst[r] - mnew) * CEXP);
        mst[r] = mnew;
        float ssum = 0.f;
        #pragma unroll
        for (int jn = 0; jn < 4; ++jn) {
          float p = __builtin_exp2f((S[jn][r] - mnew) * CEXP);
          S[jn][r] = p;
          ssum += p;
        }
        ssum = rowsum16(ssum);
        lst[r] = lst[r] * a + ssum;
        al[r] = a;
      }
      #pragma unroll
      for (int f = 0; f < 8; ++f) {
        O[f][0] *= al[0]; O[f][1] *= al[1]; O[f][2] *= al[2]; O[f][3] *= al[3];
      }

      // P (C-layout) -> per-wave LDS; same-wave DS order guarantees RAW
      #pragma unroll
      for (int jn = 0; jn < 4; ++jn)
        #pragma unroll
        for (int r = 0; r < 4; ++r) {
          int row = quad * 4 + r;
          __bf16 h = (__bf16)S[jn][r];
          Pw[row * 64 + (((jn * 2 + (n >> 3)) ^ (row & 7)) << 3) + (n & 7)]
              = __builtin_bit_cast(u16, h);
        }

      // ---- O += P * V  (16 MFMAs, 2+16 b128 reads) ----
      #pragma unroll
      for (int kc = 0; kc < 2; ++kc) {
        B8 ta;   // A-frag: P[m=n][k=kc*32+quad*8+j]
        ta.u = *(const uint4*)(&Pw[n * 64 + (((kc * 4 + quad) ^ (n & 7)) << 3)]);
        bf16x8 af = ta.v;
        #pragma unroll
        for (int f = 0; f < 8; ++f) {
          int d = f * 16 + n;                 // d&7 == n&7
          B8 bb;   // B-frag: V[k=kv][n=d] from d-major sV, unswizzle
          bb.u = *(const uint4*)(&Vg[d * 64 + (((kc * 4 + quad) ^ (n & 7)) << 3)]);
          O[f] = __builtin_amdgcn_mfma_f32_16x16x32_bf16(af, bb.v, O[f], 0, 0, 0);
        }
      }
    }

    __syncthreads();                   // barrier2: all waves done reading super-iter i
    if (tn < nt) { kstore(); vstore(); }   // regs -> LDS for super-iter i+1
  }

  // ---- cross-group merge (group 1 -> LDS, group 0 combines) + epilogue ----
  // After the loop's final barrier2, all LDS reads are done; sK/sV/sP reusable.
  if (grp == 1) {
    float* ob = ((qw < 4) ? (float*)sK : (float*)sV) + (qw & 3) * 2048 + lane * 32;
    #pragma unroll
    for (int f = 0; f < 8; ++f)
      #pragma unroll
      for (int r = 0; r < 4; ++r)
        ob[f * 4 + r] = O[f][r];
    float* sb = (float*)sP + qw * 512 + lane * 8;
    #pragma unroll
    for (int r = 0; r < 4; ++r) { sb[r] = mst[r]; sb[4 + r] = lst[r]; }
  }
  __syncthreads();
  if (grp == 0) {
    const float* ob = ((qw < 4) ? (const float*)sK : (const float*)sV) + (qw & 3) * 2048 + lane * 32;
    const float* sb = (const float*)sP + qw * 512 + lane * 8;
    #pragma unroll
    for (int r = 0; r < 4; ++r) {
      const float m1 = sb[r], l1 = sb[4 + r];
      const float m  = fmaxf(mst[r], m1);
      const float a0 = __builtin_exp2f((mst[r] - m) * CEXP);  // exp2(-inf)=0 handles empties
      const float a1 = __builtin_exp2f((m1 - m) * CEXP);
      const float rl = 1.0f / (lst[r] * a0 + l1 * a1);
      const int qrow = qrow0 + quad * 4 + r;
      float* op = og + (size_t)(b * NQ + qrow) * ND + n;
      #pragma unroll
      for (int f = 0; f < 8; ++f)
        op[f * 16] = (O[f][r] * a0 + ob[f * 4 + r] * a1) * rl;
    }
  }
}

extern "C" void kernel_launch(void* const* d_in, const int* in_sizes, int n_in,
                              void* d_out, int out_size, void* d_ws, size_t ws_size,
                              hipStream_t stream) {
  const float* q  = (const float*)d_in[0];
  const float* k  = (const float*)d_in[1];
  const float* v  = (const float*)d_in[2];
  const int*  vl  = (const int*)d_in[3];
  float* out = (float*)d_out;
  (void)d_ws; (void)ws_size;

  hipLaunchKernelGGL(flash_fwd, dim3(256), dim3(1024), 0, stream, q, k, v, vl, out);
}